// Round 1
// baseline (2673.162 us; speedup 1.0000x reference)
//
#include <hip/hip_runtime.h>
#include <math.h>

#define NV 100000
#define NE 3200000
#define NK 16
#define NT 4

__global__ __launch_bounds__(256) void zero_out_kernel(float4* __restrict__ out, int n4) {
    int i = blockIdx.x * blockDim.x + threadIdx.x;
    if (i < n4) out[i] = make_float4(0.f, 0.f, 0.f, 0.f);
}

__global__ __launch_bounds__(256) void atomic_conv_edge_kernel(
    const float* __restrict__ feat,       // (V,1) atom type ids as float
    const float* __restrict__ dist,       // (E,1)
    const int*   __restrict__ src,        // (E,)
    const int*   __restrict__ dst,        // (E,)
    const float* __restrict__ cutoffs,    // (K,)
    const float* __restrict__ means,      // (K,)
    const float* __restrict__ scaling,    // (K,)
    const float* __restrict__ feats_use,  // (T,)
    float* __restrict__ out)              // (V, T*K)
{
    int e = blockIdx.x * blockDim.x + threadIdx.x;
    if (e >= NE) return;

    float d = dist[e];
    int s = src[e];
    int v = dst[e];
    float fv = feat[s];

    // one-hot type index (reference: feat == features_to_use)
    int ty = -1;
#pragma unroll
    for (int t = 0; t < NT; ++t) {
        if (fv == feats_use[t]) ty = t;
    }
    if (ty < 0) return;  // all-zero one-hot row contributes nothing

    float* o = out + (size_t)v * (NT * NK) + (size_t)ty * NK;

    const float PI = 3.14159265358979323846f;
#pragma unroll
    for (int k = 0; k < NK; ++k) {
        float c  = cutoffs[k];
        float m  = means[k];
        float sc = scaling[k];
        float dm = d - m;
        float rbf  = __expf(-sc * dm * dm);
        float cosv = 0.5f * (__cosf(PI * d / c) + 1.0f);
        float he = (d <= c) ? rbf * cosv : 0.0f;
        __hip_atomic_fetch_add(o + k, he, __ATOMIC_RELAXED, __HIP_MEMORY_SCOPE_AGENT);
    }
}

extern "C" void kernel_launch(void* const* d_in, const int* in_sizes, int n_in,
                              void* d_out, int out_size, void* d_ws, size_t ws_size,
                              hipStream_t stream) {
    const float* feat      = (const float*)d_in[0];
    const float* dist      = (const float*)d_in[1];
    const int*   src       = (const int*)d_in[2];
    const int*   dst       = (const int*)d_in[3];
    const float* cutoffs   = (const float*)d_in[4];
    const float* means     = (const float*)d_in[5];
    const float* scaling   = (const float*)d_in[6];
    const float* feats_use = (const float*)d_in[7];
    float* out = (float*)d_out;

    // out_size = V*T*K = 6,400,000 floats (divisible by 4)
    int n4 = out_size / 4;
    zero_out_kernel<<<(n4 + 255) / 256, 256, 0, stream>>>((float4*)out, n4);

    atomic_conv_edge_kernel<<<(NE + 255) / 256, 256, 0, stream>>>(
        feat, dist, src, dst, cutoffs, means, scaling, feats_use, out);
}

// Round 2
// 475.791 us; speedup vs baseline: 5.6184x; 5.6184x over previous
//
#include <hip/hip_runtime.h>
#include <math.h>

#define NV 100000
#define NE 3200000
#define NK 16
#define NT 4
#define PI_F 3.14159265358979323846f

// ---------------- fallback path (R1 atomic kernel) ----------------

__global__ __launch_bounds__(256) void zero_out_kernel(float4* __restrict__ out, int n4) {
    int i = blockIdx.x * blockDim.x + threadIdx.x;
    if (i < n4) out[i] = make_float4(0.f, 0.f, 0.f, 0.f);
}

__global__ __launch_bounds__(256) void atomic_conv_edge_kernel(
    const float* __restrict__ feat, const float* __restrict__ dist,
    const int* __restrict__ src, const int* __restrict__ dst,
    const float* __restrict__ cutoffs, const float* __restrict__ means,
    const float* __restrict__ scaling, const float* __restrict__ feats_use,
    float* __restrict__ out)
{
    int e = blockIdx.x * blockDim.x + threadIdx.x;
    if (e >= NE) return;
    float d = dist[e];
    int s = src[e];
    int v = dst[e];
    float fv = feat[s];
    int ty = -1;
#pragma unroll
    for (int t = 0; t < NT; ++t) if (fv == feats_use[t]) ty = t;
    if (ty < 0) return;
    float* o = out + (size_t)v * (NT * NK) + (size_t)ty * NK;
#pragma unroll
    for (int k = 0; k < NK; ++k) {
        float c = cutoffs[k], m = means[k], sc = scaling[k];
        float dm = d - m;
        float rbf = __expf(-sc * dm * dm);
        float cosv = 0.5f * (__cosf(PI_F * d / c) + 1.0f);
        float he = (d <= c) ? rbf * cosv : 0.0f;
        __hip_atomic_fetch_add(o + k, he, __ATOMIC_RELAXED, __HIP_MEMORY_SCOPE_AGENT);
    }
}

// ---------------- counting-sort + gather path ----------------

__global__ __launch_bounds__(256) void zero_int_kernel(int* __restrict__ p, int n) {
    int i = blockIdx.x * blockDim.x + threadIdx.x;
    if (i < n) p[i] = 0;
}

__global__ __launch_bounds__(256) void hist_kernel(const int* __restrict__ dst,
                                                   int* __restrict__ count) {
    int e = blockIdx.x * blockDim.x + threadIdx.x;
    if (e >= NE) return;
    __hip_atomic_fetch_add(count + dst[e], 1, __ATOMIC_RELAXED, __HIP_MEMORY_SCOPE_AGENT);
}

// per-block exclusive scan of count -> excl (in offsetArr), block sums -> bsums
__global__ __launch_bounds__(256) void scan1_kernel(const int* __restrict__ count,
                                                    int* __restrict__ excl,
                                                    int* __restrict__ bsums) {
    __shared__ int s[256];
    int tid = threadIdx.x;
    int i = blockIdx.x * 256 + tid;
    int x = (i < NV) ? count[i] : 0;
    s[tid] = x;
    __syncthreads();
#pragma unroll
    for (int off = 1; off < 256; off <<= 1) {
        int t = (tid >= off) ? s[tid - off] : 0;
        __syncthreads();
        s[tid] += t;
        __syncthreads();
    }
    if (i < NV) excl[i] = s[tid] - x;
    if (tid == 255) bsums[blockIdx.x] = s[255];
}

// single-block exclusive scan of block sums (nb <= 512)
__global__ __launch_bounds__(512) void scan2_kernel(int* __restrict__ bsums, int nb) {
    __shared__ int s[512];
    int tid = threadIdx.x;
    int x = (tid < nb) ? bsums[tid] : 0;
    s[tid] = x;
    __syncthreads();
#pragma unroll
    for (int off = 1; off < 512; off <<= 1) {
        int t = (tid >= off) ? s[tid - off] : 0;
        __syncthreads();
        s[tid] += t;
        __syncthreads();
    }
    if (tid < nb) bsums[tid] = s[tid] - x;
}

// combine: offsetArr[i] += bsums[block]; cursor copy; offsetArr[NV] = NE
__global__ __launch_bounds__(256) void scan3_kernel(int* __restrict__ offsetArr,
                                                    const int* __restrict__ bsums,
                                                    int* __restrict__ cursor) {
    int i = blockIdx.x * 256 + threadIdx.x;
    if (i < NV) {
        int o = offsetArr[i] + bsums[i >> 8];
        offsetArr[i] = o;
        cursor[i] = o;
    }
    if (i == 0) offsetArr[NV] = NE;
}

__global__ __launch_bounds__(256) void scatter_kernel(
    const float* __restrict__ feat, const float* __restrict__ dist,
    const int* __restrict__ src, const int* __restrict__ dst,
    const float* __restrict__ feats_use,
    int* __restrict__ cursor, float2* __restrict__ payload) {
    int e = blockIdx.x * blockDim.x + threadIdx.x;
    if (e >= NE) return;
    float d = dist[e];
    int s = src[e];
    int v = dst[e];
    float fv = feat[s];
    int ty = -1;
#pragma unroll
    for (int t = 0; t < NT; ++t) if (fv == feats_use[t]) ty = t;
    int pos = __hip_atomic_fetch_add(cursor + v, 1, __ATOMIC_RELAXED, __HIP_MEMORY_SCOPE_AGENT);
    payload[pos] = make_float2(d, (float)ty);
}

// one wave (64 lanes) per node; lane l owns output column l = ty*16 + k
__global__ __launch_bounds__(256) void reduce_kernel(
    const float2* __restrict__ payload, const int* __restrict__ offs,
    const float* __restrict__ cutoffs, const float* __restrict__ means,
    const float* __restrict__ scaling, float* __restrict__ out) {
    int wave = threadIdx.x >> 6;
    int lane = threadIdx.x & 63;
    int v = blockIdx.x * 4 + wave;
    if (v >= NV) return;
    int n0 = offs[v];
    int n1 = offs[v + 1];
    int ty_l = lane >> 4;
    int k_l = lane & 15;
    float m = means[k_l];
    float sc = scaling[k_l];
    float c = cutoffs[k_l];
    float w = PI_F / c;
    float tyf_l = (float)ty_l;
    float acc = 0.f;
    for (int base = n0; base < n1; base += 64) {
        int idx = base + lane;
        float2 p = (idx < n1) ? payload[idx] : make_float2(0.f, -1.f);
        int cnt = n1 - base;
        if (cnt > 64) cnt = 64;
        for (int j = 0; j < cnt; ++j) {
            float d = __shfl(p.x, j);
            float tyf = __shfl(p.y, j);
            float dm = d - m;
            float rbf = __expf(-sc * dm * dm);
            float cosv = 0.5f * (__cosf(w * d) + 1.0f);
            float he = (d <= c) ? rbf * cosv : 0.0f;
            if (tyf == tyf_l) acc += he;
        }
    }
    out[(size_t)v * 64 + lane] = acc;
}

extern "C" void kernel_launch(void* const* d_in, const int* in_sizes, int n_in,
                              void* d_out, int out_size, void* d_ws, size_t ws_size,
                              hipStream_t stream) {
    const float* feat      = (const float*)d_in[0];
    const float* dist      = (const float*)d_in[1];
    const int*   src       = (const int*)d_in[2];
    const int*   dst       = (const int*)d_in[3];
    const float* cutoffs   = (const float*)d_in[4];
    const float* means     = (const float*)d_in[5];
    const float* scaling   = (const float*)d_in[6];
    const float* feats_use = (const float*)d_in[7];
    float* out = (float*)d_out;

    // workspace layout
    size_t off = 0;
    auto alloc = [&](size_t bytes) {
        size_t cur = off;
        off = (off + bytes + 255) & ~(size_t)255;
        return cur;
    };
    size_t o_count  = alloc((size_t)NV * 4);
    size_t o_offset = alloc((size_t)(NV + 1) * 4);
    size_t o_cursor = alloc((size_t)NV * 4);
    size_t o_bsums  = alloc(512 * 4);
    size_t o_payload = alloc((size_t)NE * 8);
    size_t needed = off;

    if (ws_size < needed) {
        // fallback: pure-atomic path
        int n4 = out_size / 4;
        zero_out_kernel<<<(n4 + 255) / 256, 256, 0, stream>>>((float4*)out, n4);
        atomic_conv_edge_kernel<<<(NE + 255) / 256, 256, 0, stream>>>(
            feat, dist, src, dst, cutoffs, means, scaling, feats_use, out);
        return;
    }

    char* ws = (char*)d_ws;
    int* count     = (int*)(ws + o_count);
    int* offsetArr = (int*)(ws + o_offset);
    int* cursor    = (int*)(ws + o_cursor);
    int* bsums     = (int*)(ws + o_bsums);
    float2* payload = (float2*)(ws + o_payload);

    const int nb = (NV + 255) / 256;  // 391

    zero_int_kernel<<<(NV + 255) / 256, 256, 0, stream>>>(count, NV);
    zero_int_kernel<<<2, 256, 0, stream>>>(bsums, 512);

    hist_kernel<<<(NE + 255) / 256, 256, 0, stream>>>(dst, count);

    scan1_kernel<<<nb, 256, 0, stream>>>(count, offsetArr, bsums);
    scan2_kernel<<<1, 512, 0, stream>>>(bsums, nb);
    scan3_kernel<<<nb, 256, 0, stream>>>(offsetArr, bsums, cursor);

    scatter_kernel<<<(NE + 255) / 256, 256, 0, stream>>>(
        feat, dist, src, dst, feats_use, cursor, payload);

    reduce_kernel<<<(NV + 3) / 4, 256, 0, stream>>>(
        payload, offsetArr, cutoffs, means, scaling, out);
}